// Round 19
// baseline (550.874 us; speedup 1.0000x reference)
//
#include <hip/hip_runtime.h>

typedef unsigned short u16;
typedef unsigned int   u32;
typedef __attribute__((ext_vector_type(2))) unsigned int u32x2;
typedef __attribute__((ext_vector_type(4))) float f32x4;
typedef __attribute__((ext_vector_type(8))) short s16x8;
typedef __attribute__((ext_vector_type(4))) _Float16 f16x4;
typedef __attribute__((ext_vector_type(8))) _Float16 f16x8;

#define B_   2
#define T_   2048
#define D_   4096
#define H_   32
#define HKV_ 8
#define HD_  128
#define NQKV 6144
#define M_   (B_*T_)   // 4096

__device__ __forceinline__ u16 f2bf(float f){
  u32 u = __float_as_uint(f);
  u += 0x7fffu + ((u >> 16) & 1u);
  return (u16)(u >> 16);
}
__device__ __forceinline__ float bf2f(u16 h){
  return __uint_as_float(((u32)h) << 16);
}
__device__ __forceinline__ void gload16(const void* g, void* l){
  __builtin_amdgcn_global_load_lds(
      (const __attribute__((address_space(1))) u32*)g,
      (__attribute__((address_space(3))) u32*)l, 16, 0, 0);
}

// ======== k_prep: x->bf16 convert + all 4 weight transposes in ONE launch ========
__global__ void k_prep(const float* __restrict__ x,
                       const float* __restrict__ wq, const float* __restrict__ wk,
                       const float* __restrict__ wv, const float* __restrict__ wo,
                       u16* __restrict__ Xb, u16* __restrict__ Wt,
                       u16* __restrict__ Wot){
  __shared__ float tile[64][65];
  const int z = blockIdx.z;
  const int tid = threadIdx.x;
  if (z == 4) {                      // ---- convert x: f32 -> bf16 ----
    size_t base = ((size_t)blockIdx.y * 64 + blockIdx.x) * 1024 + tid;
    #pragma unroll
    for (int r = 0; r < 4; r++) {
      size_t i = base + r * 256;
      float4 v = reinterpret_cast<const float4*>(x)[i];
      u32 lo = (u32)f2bf(v.x) | ((u32)f2bf(v.y) << 16);
      u32 hi = (u32)f2bf(v.z) | ((u32)f2bf(v.w) << 16);
      u32x2 p; p.x = lo; p.y = hi;
      reinterpret_cast<u32x2*>(Xb)[i] = p;
    }
    return;
  }
  const float* in; u16* out; int N;
  if      (z == 0) { in = wq; out = Wt;                        N = 4096; }
  else if (z == 1) { in = wk; out = Wt + (size_t)D_ * D_;      N = 1024; }
  else if (z == 2) { in = wv; out = Wt + (size_t)5120 * D_;    N = 1024; }
  else             { in = wo; out = Wot;                       N = 4096; }
  const int n0 = blockIdx.x * 64, k0 = blockIdx.y * 64;
  if (n0 >= N) return;
  const int tx = tid & 15, ty = tid >> 4;
  #pragma unroll
  for (int rr = 0; rr < 4; rr++) {
    int r = ty + 16 * rr;
    float4 v = *reinterpret_cast<const float4*>(in + (size_t)(k0 + r) * N + n0 + 4 * tx);
    tile[r][4 * tx + 0] = v.x; tile[r][4 * tx + 1] = v.y;
    tile[r][4 * tx + 2] = v.z; tile[r][4 * tx + 3] = v.w;
  }
  __syncthreads();
  #pragma unroll
  for (int ni = 0; ni < 4; ni++) {
    int nn = ty + 16 * ni;
    ushort4 o;
    o.x = f2bf(tile[4 * tx + 0][nn]);
    o.y = f2bf(tile[4 * tx + 1][nn]);
    o.z = f2bf(tile[4 * tx + 2][nn]);
    o.w = f2bf(tile[4 * tx + 3][nn]);
    *reinterpret_cast<ushort4*>(out + (size_t)(n0 + nn) * D_ + k0 + 4 * tx) = o;
  }
}

// ---------------- GEMM 128x128 (proven 945 TF) — KV-GEMM (512 blocks = 1 round) ----------------
// ldc added so C can be a column-slice of a wider matrix (C1 cols 4096..6143).
template<int OUT_F32>
__global__ __launch_bounds__(256, 2) void k_gemm(
    const u16* __restrict__ A, const u16* __restrict__ Bt,
    void* __restrict__ Cv, int M, int N, int K, int ldc)
{
  __shared__ __attribute__((aligned(16))) unsigned char smem[32768];
  unsigned char* As = smem;            // [128 rows][128 B]  (64 bf16/row)
  unsigned char* Bs = smem + 16384;
  const int tid = threadIdx.x;
  const int w = tid >> 6, l = tid & 63;
  const int m0 = blockIdx.y * 128, n0 = blockIdx.x * 128;
  const int wm = (w >> 1) * 64, wn = (w & 1) * 64;
  f32x4 acc[4][4];
  #pragma unroll
  for (int i = 0; i < 4; i++)
    #pragma unroll
    for (int j = 0; j < 4; j++)
      acc[i][j] = f32x4{0.f, 0.f, 0.f, 0.f};

  const int srcoff = 8 * ((l & 7) ^ ((l >> 3) & 7));
  const int subrow = l >> 3;

  for (int k0 = 0; k0 < K; k0 += 64) {
    if (k0) __syncthreads();
    #pragma unroll
    for (int i = 0; i < 4; i++) {
      int chunk = 4 * w + i;
      int row = chunk * 8 + subrow;
      gload16(A  + (size_t)(m0 + row) * K + k0 + srcoff, As + chunk * 1024);
      gload16(Bt + (size_t)(n0 + row) * K + k0 + srcoff, Bs + chunk * 1024);
    }
    asm volatile("s_waitcnt vmcnt(0)" ::: "memory");
    __syncthreads();
    #pragma unroll
    for (int kk = 0; kk < 2; kk++) {
      s16x8 a[4], b[4];
      const int co = kk * 64 + 16 * (l >> 4);
      #pragma unroll
      for (int mi = 0; mi < 4; mi++) {
        int r = wm + 16 * mi + (l & 15);
        a[mi] = *reinterpret_cast<const s16x8*>(As + r * 128 + (co ^ ((r & 7) << 4)));
      }
      #pragma unroll
      for (int ni = 0; ni < 4; ni++) {
        int r = wn + 16 * ni + (l & 15);
        b[ni] = *reinterpret_cast<const s16x8*>(Bs + r * 128 + (co ^ ((r & 7) << 4)));
      }
      #pragma unroll
      for (int mi = 0; mi < 4; mi++)
        #pragma unroll
        for (int ni = 0; ni < 4; ni++)
          acc[mi][ni] = __builtin_amdgcn_mfma_f32_16x16x32_bf16(a[mi], b[ni], acc[mi][ni], 0, 0, 0);
    }
  }
  const int g = l >> 4, c = l & 15;
  #pragma unroll
  for (int mi = 0; mi < 4; mi++)
    #pragma unroll
    for (int ni = 0; ni < 4; ni++)
      #pragma unroll
      for (int r = 0; r < 4; r++) {
        int m = m0 + wm + 16 * mi + 4 * g + r;
        int n = n0 + wn + 16 * ni + c;
        float v = acc[mi][ni][r];
        if (OUT_F32) reinterpret_cast<float*>(Cv)[(size_t)m * ldc + n] = v;
        else         reinterpret_cast<u16*>(Cv)[(size_t)m * ldc + n] = f2bf(v);
      }
}

// ---- shared macros for the 8-phase GEMM ----
#define BARX  asm volatile("s_barrier" ::: "memory")
#define PRIO1 __builtin_amdgcn_s_setprio(1)
#define PRIO0 __builtin_amdgcn_s_setprio(0)
#define VM4   asm volatile("s_waitcnt vmcnt(4)" ::: "memory")
#define VM0   asm volatile("s_waitcnt vmcnt(0)" ::: "memory")
#define LGKM0 do { asm volatile("s_waitcnt lgkmcnt(0)" ::: "memory"); \
                   __builtin_amdgcn_sched_barrier(0); } while (0)

// ======== GEMM 256x256, 8-phase — Q-GEMM and out-proj (256 blocks = 1/CU, tail-free) ========
#define AS_(b) (smem + (b) * 65536)
#define BS_(b) (smem + (b) * 65536 + 32768)
#define STAGE_HA(buf, half, kt) { \
  _Pragma("unroll") for (int r2 = 0; r2 < 2; r2++) { \
    int rw = (half) * 128 + r2 * 64 + w * 8; \
    gload16(A + (size_t)(m0 + rw + subrow) * K + (kt) * 64 + srcoff, \
            AS_(buf) + rw * 128); } }
#define STAGE_HB(buf, half, kt) { \
  _Pragma("unroll") for (int r2 = 0; r2 < 2; r2++) { \
    int rw = (half) * 128 + r2 * 64 + w * 8; \
    gload16(Bt + (size_t)(n0 + rw + subrow) * K + (kt) * 64 + srcoff, \
            BS_(buf) + rw * 128); } }
#define RD_A2(buf, p) { \
  _Pragma("unroll") for (int rt = 0; rt < 2; rt++) { \
    int row = wr * 128 + (p) * 32 + rt * 16 + c; \
    const unsigned char* ptr = AS_(buf) + row * 128; \
    int sw = (row & 7) << 4; \
    af[rt][0] = *(const s16x8*)(ptr + ((16 * g) ^ sw)); \
    af[rt][1] = *(const s16x8*)(ptr + ((64 + 16 * g) ^ sw)); } }
#define RD_B8(buf) { \
  _Pragma("unroll") for (int ni = 0; ni < 4; ni++) { \
    int row = wc * 64 + ni * 16 + c; \
    const unsigned char* ptr = BS_(buf) + row * 128; \
    int sw = (row & 7) << 4; \
    bfr[ni][0] = *(const s16x8*)(ptr + ((16 * g) ^ sw)); \
    bfr[ni][1] = *(const s16x8*)(ptr + ((64 + 16 * g) ^ sw)); } }
#define MFP(p) { \
  _Pragma("unroll") for (int rt = 0; rt < 2; rt++) \
  _Pragma("unroll") for (int ni = 0; ni < 4; ni++) \
  _Pragma("unroll") for (int kk = 0; kk < 2; kk++) \
    acc[(p) * 2 + rt][ni] = __builtin_amdgcn_mfma_f32_16x16x32_bf16( \
        af[rt][kk], bfr[ni][kk], acc[(p) * 2 + rt][ni], 0, 0, 0); }

template<int OUT_F32>
__global__ __launch_bounds__(512, 1) void k_gemm8(
    const u16* __restrict__ A, const u16* __restrict__ Bt,
    void* __restrict__ Cv, int M, int N, int K, int ldc)
{
  __shared__ __attribute__((aligned(16))) unsigned char smem[131072];
  const int tid = threadIdx.x;
  const int w = tid >> 6, l = tid & 63;
  const int c = l & 15, g = l >> 4;
  const int wr = w >> 2, wc = w & 3;

  const int nbx = N >> 8;
  const int nwg = nbx * (M >> 8);
  const int orig = blockIdx.x;
  const int id = (orig & 7) * (nwg >> 3) + (orig >> 3);
  const int m0 = (id / nbx) << 8;
  const int n0 = (id % nbx) << 8;

  const int srcoff = 8 * ((l & 7) ^ ((l >> 3) & 7));
  const int subrow = l >> 3;

  f32x4 acc[8][4];
  #pragma unroll
  for (int i = 0; i < 8; i++)
    #pragma unroll
    for (int j = 0; j < 4; j++)
      acc[i][j] = f32x4{0.f, 0.f, 0.f, 0.f};
  s16x8 af[2][2], bfr[4][2];

  STAGE_HB(0, 0, 0); STAGE_HB(0, 1, 0);
  STAGE_HA(0, 0, 0); STAGE_HA(0, 1, 0);
  STAGE_HB(1, 0, 1); STAGE_HB(1, 1, 1);
  VM4; BARX;

  const int NT2 = K >> 7;
  for (int it = 0; it < NT2; ++it) {
    const int tA = 2 * it, tB = 2 * it + 1;
    const bool st = (it < NT2 - 1);
    RD_A2(0, 0); RD_B8(0); STAGE_HA(1, 0, tB);
    BARX; LGKM0; PRIO1; MFP(0); PRIO0; BARX;
    RD_A2(0, 1); STAGE_HA(1, 1, tB);
    BARX; LGKM0; PRIO1; MFP(1); PRIO0; BARX;
    RD_A2(0, 2); if (st) STAGE_HB(0, 0, tA + 2);
    BARX; LGKM0; PRIO1; MFP(2); PRIO0; BARX;
    RD_A2(0, 3); if (st) STAGE_HB(0, 1, tA + 2);
    BARX; LGKM0; PRIO1; MFP(3); PRIO0;
    if (st) { VM4; } else { VM0; }
    BARX;
    RD_A2(1, 0); RD_B8(1); if (st) STAGE_HA(0, 0, tA + 2);
    BARX; LGKM0; PRIO1; MFP(0); PRIO0; BARX;
    RD_A2(1, 1); if (st) STAGE_HA(0, 1, tA + 2);
    BARX; LGKM0; PRIO1; MFP(1); PRIO0; BARX;
    RD_A2(1, 2); if (st) STAGE_HB(1, 0, tB + 2);
    BARX; LGKM0; PRIO1; MFP(2); PRIO0; BARX;
    RD_A2(1, 3); if (st) STAGE_HB(1, 1, tB + 2);
    BARX; LGKM0; PRIO1; MFP(3); PRIO0;
    if (st) { VM4; }
    BARX;
  }

  #pragma unroll
  for (int mi = 0; mi < 8; mi++)
    #pragma unroll
    for (int ni = 0; ni < 4; ni++)
      #pragma unroll
      for (int r = 0; r < 4; r++) {
        int m = m0 + wr * 128 + 16 * mi + 4 * g + r;
        int n = n0 + wc * 64 + 16 * ni + c;
        float v = acc[mi][ni][r];
        if (OUT_F32) reinterpret_cast<float*>(Cv)[(size_t)m * ldc + n] = v;
        else         reinterpret_cast<u16*>(Cv)[(size_t)m * ldc + n] = f2bf(v);
      }
}

// ======== k_rope: RoPE-Q (in place) + RoPE-K (-> swizzled Kg) in ONE launch ========
__global__ void k_rope(u16* __restrict__ C1, const float* __restrict__ fc,
                       const float* __restrict__ fs, unsigned char* __restrict__ Kg){
  const int bid = blockIdx.x;
  if (bid < 32768) {
    int idx = bid * 256 + threadIdx.x;        // M_ * 2048 pairs
    int m = idx >> 11, p = idx & 2047;
    int h = p >> 6, i = p & 63;
    int t = m & (T_ - 1);
    u32* ptr = reinterpret_cast<u32*>(C1 + (size_t)m * NQKV + h * HD_ + 2 * i);
    u32 u = *ptr;
    float x0 = __uint_as_float(u << 16);
    float x1 = __uint_as_float(u & 0xffff0000u);
    float cc = fc[t * 64 + i], ss = fs[t * 64 + i];
    float o0 = x0 * cc - x1 * ss;
    float o1 = x0 * ss + x1 * cc;
    *ptr = (u32)f2bf(o0) | ((u32)f2bf(o1) << 16);
  } else {
    int idx = (bid - 32768) * 256 + threadIdx.x;  // M_ * 512 pairs
    int m = idx >> 9, p = idx & 511;
    int kh = p >> 6, i = p & 63;
    int b = m >> 11, t = m & (T_ - 1);
    u32 u = *reinterpret_cast<const u32*>(C1 + (size_t)m * NQKV + D_ + kh * HD_ + 2 * i);
    float x0 = __uint_as_float(u << 16);
    float x1 = __uint_as_float(u & 0xffff0000u);
    float cc = fc[t * 64 + i], ss = fs[t * 64 + i];
    float o0 = x0 * cc - x1 * ss;
    float o1 = x0 * ss + x1 * cc;
    u32 packed = (u32)f2bf(o0) | ((u32)f2bf(o1) << 16);
    unsigned char* Kbb = Kg + (size_t)(b * HKV_ + kh) * 524288;
    int swb = (((i >> 2) ^ (t & 7)) << 4) | (4 * (i & 3));
    *reinterpret_cast<u32*>(Kbb + (size_t)t * 256 + swb) = packed;
  }
}

// ---- V -> fp16 V^T, tile-major [b][kh][T/64][128][64], kv-bit-permuted + swizzled ----
__global__ void k_v_trans(const u16* __restrict__ C1, unsigned char* __restrict__ Vg){
  __shared__ float tile[32][33];
  int bz = blockIdx.z;                        // b*8+kh
  int t0 = blockIdx.x * 32, d0 = blockIdx.y * 32;
  int tx = threadIdx.x, ty = threadIdx.y;
  int b = bz >> 3, kh = bz & 7;
  const u16* src = C1 + (size_t)(b * T_) * NQKV + D_ + HKV_ * HD_ + kh * HD_;
  #pragma unroll
  for (int i = ty; i < 32; i += 8)
    tile[i][tx] = bf2f(src[(size_t)(t0 + i) * NQKV + d0 + tx]);
  __syncthreads();
  unsigned char* Vbb = Vg + (size_t)bz * 524288;
  #pragma unroll
  for (int i = ty; i < 32; i += 8) {
    int d = d0 + i;
    int k = t0 + tx;
    int tt = k >> 6, kv = k & 63;
    int pp = (kv & 0x23) | ((kv & 0x10) >> 2) | ((kv & 0x0C) << 1);
    int swb = (((pp >> 3) ^ (d & 7)) << 4) | (2 * (pp & 7));
    *reinterpret_cast<_Float16*>(Vbb + (size_t)tt * 16384 + d * 128 + swb) =
        (_Float16)tile[tx][i];
  }
}

// ------- attention: r15 (best): K dbuf LDS (32KB) + V single-buf LDS (16KB) -------
__global__ __launch_bounds__(256, 2) void k_attn(
    const u16* __restrict__ Q,              // C1 roped, (B*T) x NQKV
    const unsigned char* __restrict__ Kg,   // pre-swizzled tiles
    const unsigned char* __restrict__ Vg,   // pre-swizzled permuted tiles
    u16* __restrict__ Ob)                   // (B*T) x 4096
{
  __shared__ __attribute__((aligned(16))) unsigned char smem[49152];
  const int tid = threadIdx.x;
  const int w = tid >> 6, l = tid & 63;
  const int c = l & 15, g = l >> 4;
  const int q0 = blockIdx.x * 128 + w * 32;
  const int h = blockIdx.y, b = blockIdx.z;
  const int kh = h >> 2;
  const unsigned char* Kb_ = Kg + (size_t)(b * HKV_ + kh) * 524288;
  const unsigned char* Vb_ = Vg + (size_t)(b * HKV_ + kh) * 524288;

  const float SCL2 = 0.08838834764831845f * 1.4426950408889634f; // 1/sqrt(128)*log2e
  const float OFF2 = 14.4269504f;                                // 10*log2e

  s16x8 qf[2][4];
  #pragma unroll
  for (int qt = 0; qt < 2; qt++)
    #pragma unroll
    for (int ci = 0; ci < 4; ci++)
      qf[qt][ci] = *reinterpret_cast<const s16x8*>(
          Q + (size_t)(b * T_ + q0 + 16 * qt + c) * NQKV + h * HD_ + 32 * ci + 8 * g);

  f32x4 o[2][8];
  #pragma unroll
  for (int qt = 0; qt < 2; qt++)
    #pragma unroll
    for (int i = 0; i < 8; i++) o[qt][i] = f32x4{0.f, 0.f, 0.f, 0.f};
  float lsum[2] = {0.f, 0.f};

  auto stageK = [&](int bi, int tt) {
    const unsigned char* Ks = Kb_ + (size_t)tt * 16384;
    unsigned char* Kl = smem + bi * 16384;
    #pragma unroll
    for (int i = 0; i < 4; i++) {
      int ch = i * 4 + w;
      gload16(Ks + ch * 1024 + l * 16, Kl + ch * 1024);
    }
  };
  auto stageV = [&](int tt) {
    const unsigned char* Vs = Vb_ + (size_t)tt * 16384;
    unsigned char* Vl = smem + 32768;
    #pragma unroll
    for (int i = 0; i < 4; i++) {
      int ch = i * 4 + w;
      gload16(Vs + ch * 1024 + l * 16, Vl + ch * 1024);
    }
  };

  stageK(0, 0);
  asm volatile("s_waitcnt vmcnt(0)" ::: "memory");
  __syncthreads();

  for (int tt = 0; tt < T_ / 64; ++tt) {
    int cur = tt & 1;
    stageV(tt);                                // V(t): 4 gloads (oldest)
    if (tt < T_ / 64 - 1) stageK(cur ^ 1, tt + 1);  // K(t+1): 4 gloads (newest)
    const unsigned char* Kl = smem + cur * 16384;
    const unsigned char* Vl = smem + 32768;

    f32x4 s[4][2];
    #pragma unroll
    for (int mi = 0; mi < 4; mi++)
      #pragma unroll
      for (int qt = 0; qt < 2; qt++) s[mi][qt] = f32x4{0.f, 0.f, 0.f, 0.f};

    #pragma unroll
    for (int mi = 0; mi < 4; mi++) {
      const int row = 16 * mi + c;
      const int sw = (row & 7) << 4;
      s16x8 kf[4];
      #pragma unroll
      for (int ci = 0; ci < 4; ci++)
        kf[ci] = *reinterpret_cast<const s16x8*>(Kl + row * 256 + ((64 * ci + 16 * g) ^ sw));
      #pragma unroll
      for (int qt = 0; qt < 2; qt++)
        #pragma unroll
        for (int ci = 0; ci < 4; ci++)
          s[mi][qt] = __builtin_amdgcn_mfma_f32_16x16x32_bf16(kf[ci], qf[qt][ci], s[mi][qt], 0, 0, 0);
    }

    // softmax -> packed A-frags for K=32 PV
    f16x8 pa8[2][2];
    #pragma unroll
    for (int qt = 0; qt < 2; qt++)
      #pragma unroll
      for (int mi = 0; mi < 4; mi++)
        #pragma unroll
        for (int r = 0; r < 4; r++) {
          float p = exp2f(s[mi][qt][r] * SCL2 - OFF2);
          lsum[qt] += p;
          pa8[qt][mi >> 1][(mi & 1) * 4 + r] = (_Float16)p;
        }

    // V(t) landed (counted drain: keep K(t+1) in flight)
    if (tt < T_ / 64 - 1) asm volatile("s_waitcnt vmcnt(4)" ::: "memory");
    else                  asm volatile("s_waitcnt vmcnt(0)" ::: "memory");
    __syncthreads();

    #pragma unroll
    for (int cp = 0; cp < 2; cp++)
      #pragma unroll
      for (int dc = 0; dc < 8; dc++) {
        const int d = 16 * dc + c;
        f16x8 v8 = *reinterpret_cast<const f16x8*>(
            Vl + d * 128 + ((64 * cp + 16 * g) ^ ((d & 7) << 4)));
        #pragma unroll
        for (int qt = 0; qt < 2; qt++)
          o[qt][dc] = __builtin_amdgcn_mfma_f32_16x16x32_f16(pa8[qt][cp], v8, o[qt][dc], 0, 0, 0);
      }

    // K(t+1) landed; all waves done with Vbuf -> safe to overwrite next iter
    asm volatile("s_waitcnt vmcnt(0)" ::: "memory");
    __syncthreads();
  }

  #pragma unroll
  for (int qt = 0; qt < 2; qt++) {
    lsum[qt] += __shfl_xor(lsum[qt], 16);
    lsum[qt] += __shfl_xor(lsum[qt], 32);
  }
  float inv[2][4];
  #pragma unroll
  for (int qt = 0; qt < 2; qt++)
    #pragma unroll
    for (int r = 0; r < 4; r++)
      inv[qt][r] = 1.0f / __shfl(lsum[qt], 4 * g + r, 64);

  #pragma unroll
  for (int qt = 0; qt < 2; qt++) {
    u16* Orow = Ob + (size_t)(b * T_ + q0 + 16 * qt) * D_ + h * HD_;
    #pragma unroll
    for (int dc = 0; dc < 8; dc++)
      #pragma unroll
      for (int r = 0; r < 4; r++)
        Orow[(size_t)(4 * g + r) * D_ + 16 * dc + c] = f2bf(o[qt][dc][r] * inv[qt][r]);
  }
}

// ---------------- launch ----------------
extern "C" void kernel_launch(void* const* d_in, const int* in_sizes, int n_in,
                              void* d_out, int out_size, void* d_ws, size_t ws_size,
                              hipStream_t stream)
{
  const float* x  = (const float*)d_in[0];
  const float* fc = (const float*)d_in[1];
  const float* fs = (const float*)d_in[2];
  const float* wq = (const float*)d_in[6];
  const float* wk = (const float*)d_in[7];
  const float* wv = (const float*)d_in[8];
  const float* wo = (const float*)d_in[9];

  unsigned char* w = (unsigned char*)d_ws;
  u16* Xb   = (u16*)(w);                       // 4096x4096 bf16      33,554,432 B
  u16* Wt   = (u16*)(w + 33554432ull);         // 6144x4096 bf16      50,331,648 B
  u16* Wot  = (u16*)(w + 83886080ull);         // 4096x4096 bf16      33,554,432 B
  u16* C1   = (u16*)(w + 117440512ull);        // 4096x6144 bf16      50,331,648 B
  unsigned char* Kg = w + 167772160ull;        // 16 x 512KB swizzled  8,388,608 B
  unsigned char* Vg = w + 176160768ull;        // 16 x 512KB swizzled  8,388,608 B
  u16* Ob   = (u16*)(w + 184549376ull);        // 4096x4096 bf16      33,554,432 B

  // prep: convert x + all 4 weight transposes (one launch)
  k_prep<<<dim3(64, 64, 5), 256, 0, stream>>>(x, wq, wk, wv, wo, Xb, Wt, Wot);

  // QKV split into two tail-free GEMMs:
  //   Q:  4096x4096 via 256^2 8-phase (256 blocks = 1/CU — same shape as out-proj, 1.22 PF)
  //   KV: 4096x2048 via 128^2 (512 blocks = 1 round at 2/CU)
  k_gemm8<0><<<(D_ / 256) * (M_ / 256), 512, 0, stream>>>(Xb, Wt, C1, M_, D_, D_, NQKV);
  k_gemm<0><<<dim3(2048 / 128, M_ / 128), 256, 0, stream>>>(
      Xb, Wt + (size_t)D_ * D_, C1 + D_, M_, 2048, D_, NQKV);

  // rope Q (in place) + rope K (-> Kg), one launch
  k_rope<<<40960, 256, 0, stream>>>(C1, fc, fs, Kg);
  k_v_trans<<<dim3(64, 4, 16), dim3(32, 8), 0, stream>>>(C1, Vg);

  // attn: K dbuf + V single-buf (48KB LDS), proven r15
  k_attn<<<dim3(T_ / 128, H_, B_), 256, 0, stream>>>(C1, Kg, Vg, Ob);

  // out-proj: 256^2 8-phase (256 blocks = exactly 1/CU, tail-free)
  k_gemm8<1><<<(D_ / 256) * (M_ / 256), 512, 0, stream>>>(Ob, Wot, d_out, M_, D_, D_, D_);
}

// Round 20
// 531.735 us; speedup vs baseline: 1.0360x; 1.0360x over previous
//
#include <hip/hip_runtime.h>

typedef unsigned short u16;
typedef unsigned int   u32;
typedef __attribute__((ext_vector_type(2))) unsigned int u32x2;
typedef __attribute__((ext_vector_type(4))) float f32x4;
typedef __attribute__((ext_vector_type(8))) short s16x8;
typedef __attribute__((ext_vector_type(4))) _Float16 f16x4;
typedef __attribute__((ext_vector_type(8))) _Float16 f16x8;

#define B_   2
#define T_   2048
#define D_   4096
#define H_   32
#define HKV_ 8
#define HD_  128
#define NQKV 6144
#define M_   (B_*T_)   // 4096

__device__ __forceinline__ u16 f2bf(float f){
  u32 u = __float_as_uint(f);
  u += 0x7fffu + ((u >> 16) & 1u);
  return (u16)(u >> 16);
}
__device__ __forceinline__ float bf2f(u16 h){
  return __uint_as_float(((u32)h) << 16);
}
__device__ __forceinline__ void gload16(const void* g, void* l){
  __builtin_amdgcn_global_load_lds(
      (const __attribute__((address_space(1))) u32*)g,
      (__attribute__((address_space(3))) u32*)l, 16, 0, 0);
}

// ======== k_prep: x->bf16 convert + all 4 weight transposes in ONE launch ========
__global__ void k_prep(const float* __restrict__ x,
                       const float* __restrict__ wq, const float* __restrict__ wk,
                       const float* __restrict__ wv, const float* __restrict__ wo,
                       u16* __restrict__ Xb, u16* __restrict__ Wt,
                       u16* __restrict__ Wot){
  __shared__ float tile[64][65];
  const int z = blockIdx.z;
  const int tid = threadIdx.x;
  if (z == 4) {                      // ---- convert x: f32 -> bf16 ----
    size_t base = ((size_t)blockIdx.y * 64 + blockIdx.x) * 1024 + tid;
    #pragma unroll
    for (int r = 0; r < 4; r++) {
      size_t i = base + r * 256;
      float4 v = reinterpret_cast<const float4*>(x)[i];
      u32 lo = (u32)f2bf(v.x) | ((u32)f2bf(v.y) << 16);
      u32 hi = (u32)f2bf(v.z) | ((u32)f2bf(v.w) << 16);
      u32x2 p; p.x = lo; p.y = hi;
      reinterpret_cast<u32x2*>(Xb)[i] = p;
    }
    return;
  }
  const float* in; u16* out; int N;
  if      (z == 0) { in = wq; out = Wt;                        N = 4096; }
  else if (z == 1) { in = wk; out = Wt + (size_t)D_ * D_;      N = 1024; }
  else if (z == 2) { in = wv; out = Wt + (size_t)5120 * D_;    N = 1024; }
  else             { in = wo; out = Wot;                       N = 4096; }
  const int n0 = blockIdx.x * 64, k0 = blockIdx.y * 64;
  if (n0 >= N) return;
  const int tx = tid & 15, ty = tid >> 4;
  #pragma unroll
  for (int rr = 0; rr < 4; rr++) {
    int r = ty + 16 * rr;
    float4 v = *reinterpret_cast<const float4*>(in + (size_t)(k0 + r) * N + n0 + 4 * tx);
    tile[r][4 * tx + 0] = v.x; tile[r][4 * tx + 1] = v.y;
    tile[r][4 * tx + 2] = v.z; tile[r][4 * tx + 3] = v.w;
  }
  __syncthreads();
  #pragma unroll
  for (int ni = 0; ni < 4; ni++) {
    int nn = ty + 16 * ni;
    ushort4 o;
    o.x = f2bf(tile[4 * tx + 0][nn]);
    o.y = f2bf(tile[4 * tx + 1][nn]);
    o.z = f2bf(tile[4 * tx + 2][nn]);
    o.w = f2bf(tile[4 * tx + 3][nn]);
    *reinterpret_cast<ushort4*>(out + (size_t)(n0 + nn) * D_ + k0 + 4 * tx) = o;
  }
}

// ---- shared macros for the 8-phase GEMMs ----
#define BARX  asm volatile("s_barrier" ::: "memory")
#define PRIO1 __builtin_amdgcn_s_setprio(1)
#define PRIO0 __builtin_amdgcn_s_setprio(0)
#define VM4   asm volatile("s_waitcnt vmcnt(4)" ::: "memory")
#define VM3   asm volatile("s_waitcnt vmcnt(3)" ::: "memory")
#define VM0   asm volatile("s_waitcnt vmcnt(0)" ::: "memory")
#define LGKM0 do { asm volatile("s_waitcnt lgkmcnt(0)" ::: "memory"); \
                   __builtin_amdgcn_sched_barrier(0); } while (0)

// ======== GEMM 256x192, BK=64, 8 waves, 8-phase — QKV (512 blocks = 2 rounds) ========
// n-major-within-XCD raster (r17: FETCH 410->287MB, 212->207us).
#define QAS_(b) (smem + (b) * 57344)
#define QBS_(b) (smem + (b) * 57344 + 32768)
#define Q_AU(buf, u, kt) { \
    int rw = (u) * 64 + w * 8; \
    gload16(A + (size_t)(m0 + rw + subrow) * K + (kt) * 64 + srcoff, \
            QAS_(buf) + rw * 128); }
#define Q_BU(buf, u, kt) { \
    int rw = (u) * 64 + w * 8; \
    gload16(Bt + (size_t)(n0 + rw + subrow) * K + (kt) * 64 + srcoff, \
            QBS_(buf) + rw * 128); }
#define Q_RD_A2(buf, p) { \
  _Pragma("unroll") for (int rt = 0; rt < 2; rt++) { \
    int row = wr * 128 + (p) * 32 + rt * 16 + c; \
    const unsigned char* ptr = QAS_(buf) + row * 128; \
    int sw = (row & 7) << 4; \
    af[rt][0] = *(const s16x8*)(ptr + ((16 * g) ^ sw)); \
    af[rt][1] = *(const s16x8*)(ptr + ((64 + 16 * g) ^ sw)); } }
#define Q_RD_B6(buf) { \
  _Pragma("unroll") for (int ni = 0; ni < 3; ni++) { \
    int row = wc * 48 + ni * 16 + c; \
    const unsigned char* ptr = QBS_(buf) + row * 128; \
    int sw = (row & 7) << 4; \
    bfr[ni][0] = *(const s16x8*)(ptr + ((16 * g) ^ sw)); \
    bfr[ni][1] = *(const s16x8*)(ptr + ((64 + 16 * g) ^ sw)); } }
#define Q_MFP(p) { \
  _Pragma("unroll") for (int rt = 0; rt < 2; rt++) \
  _Pragma("unroll") for (int ni = 0; ni < 3; ni++) \
  _Pragma("unroll") for (int kk = 0; kk < 2; kk++) \
    acc[(p) * 2 + rt][ni] = __builtin_amdgcn_mfma_f32_16x16x32_bf16( \
        af[rt][kk], bfr[ni][kk], acc[(p) * 2 + rt][ni], 0, 0, 0); }

__global__ __launch_bounds__(512, 1) void k_gemm8q(
    const u16* __restrict__ A, const u16* __restrict__ Bt,
    u16* __restrict__ Cv, int M, int N, int K)
{
  __shared__ __attribute__((aligned(16))) unsigned char smem[114688];
  const int tid = threadIdx.x;
  const int w = tid >> 6, l = tid & 63;
  const int c = l & 15, g = l >> 4;
  const int wr = w >> 2, wc = w & 3;

  const int nbx = N / 192;                 // 32
  const int nmy = M >> 8;                  // 16
  const int nwg = nbx * nmy;               // 512
  const int orig = blockIdx.x;
  const int id = (orig & 7) * (nwg >> 3) + (orig >> 3);
  const int m0 = (id % nmy) << 8;
  const int n0 = (id / nmy) * 192;

  const int srcoff = 8 * ((l & 7) ^ ((l >> 3) & 7));
  const int subrow = l >> 3;

  f32x4 acc[8][3];
  #pragma unroll
  for (int i = 0; i < 8; i++)
    #pragma unroll
    for (int j = 0; j < 3; j++)
      acc[i][j] = f32x4{0.f, 0.f, 0.f, 0.f};
  s16x8 af[2][2], bfr[3][2];

  Q_BU(0, 0, 0); Q_BU(0, 1, 0); Q_BU(0, 2, 0);
  Q_AU(0, 0, 0); Q_AU(0, 1, 0); Q_AU(0, 2, 0); Q_AU(0, 3, 0);
  Q_BU(1, 0, 1); Q_BU(1, 1, 1); Q_BU(1, 2, 1);
  VM3; BARX;

  const int NT2 = K >> 7;
  for (int it = 0; it < NT2; ++it) {
    const int tA = 2 * it, tB = 2 * it + 1;
    const bool st = (it < NT2 - 1);
    Q_RD_A2(0, 0); Q_RD_B6(0); Q_AU(1, 0, tB); Q_AU(1, 1, tB);
    BARX; LGKM0; PRIO1; Q_MFP(0); PRIO0; BARX;
    Q_RD_A2(0, 1); Q_AU(1, 2, tB); Q_AU(1, 3, tB);
    BARX; LGKM0; PRIO1; Q_MFP(1); PRIO0; BARX;
    Q_RD_A2(0, 2); if (st) { Q_BU(0, 0, tA + 2); Q_BU(0, 1, tA + 2); }
    BARX; LGKM0; PRIO1; Q_MFP(2); PRIO0; BARX;
    Q_RD_A2(0, 3); if (st) Q_BU(0, 2, tA + 2);
    BARX; LGKM0; PRIO1; Q_MFP(3); PRIO0;
    if (st) { VM3; } else { VM0; }
    BARX;
    Q_RD_A2(1, 0); Q_RD_B6(1); if (st) { Q_AU(0, 0, tA + 2); Q_AU(0, 1, tA + 2); }
    BARX; LGKM0; PRIO1; Q_MFP(0); PRIO0; BARX;
    Q_RD_A2(1, 1); if (st) { Q_AU(0, 2, tA + 2); Q_AU(0, 3, tA + 2); }
    BARX; LGKM0; PRIO1; Q_MFP(1); PRIO0; BARX;
    Q_RD_A2(1, 2); if (st) { Q_BU(1, 0, tB + 2); Q_BU(1, 1, tB + 2); }
    BARX; LGKM0; PRIO1; Q_MFP(2); PRIO0; BARX;
    Q_RD_A2(1, 3); if (st) Q_BU(1, 2, tB + 2);
    BARX; LGKM0; PRIO1; Q_MFP(3); PRIO0;
    if (st) { VM3; }
    BARX;
  }

  #pragma unroll
  for (int mi = 0; mi < 8; mi++)
    #pragma unroll
    for (int ni = 0; ni < 3; ni++)
      #pragma unroll
      for (int r = 0; r < 4; r++) {
        int m = m0 + wr * 128 + 16 * mi + 4 * g + r;
        int n = n0 + wc * 48 + 16 * ni + c;
        Cv[(size_t)m * N + n] = f2bf(acc[mi][ni][r]);
      }
}

// ======== GEMM 256x256, 8-phase — out-proj ONLY (256 blocks = 1/CU, tail-free) ========
#define AS_(b) (smem + (b) * 65536)
#define BS_(b) (smem + (b) * 65536 + 32768)
#define STAGE_HA(buf, half, kt) { \
  _Pragma("unroll") for (int r2 = 0; r2 < 2; r2++) { \
    int rw = (half) * 128 + r2 * 64 + w * 8; \
    gload16(A + (size_t)(m0 + rw + subrow) * K + (kt) * 64 + srcoff, \
            AS_(buf) + rw * 128); } }
#define STAGE_HB(buf, half, kt) { \
  _Pragma("unroll") for (int r2 = 0; r2 < 2; r2++) { \
    int rw = (half) * 128 + r2 * 64 + w * 8; \
    gload16(Bt + (size_t)(n0 + rw + subrow) * K + (kt) * 64 + srcoff, \
            BS_(buf) + rw * 128); } }
#define RD_A2(buf, p) { \
  _Pragma("unroll") for (int rt = 0; rt < 2; rt++) { \
    int row = wr * 128 + (p) * 32 + rt * 16 + c; \
    const unsigned char* ptr = AS_(buf) + row * 128; \
    int sw = (row & 7) << 4; \
    af[rt][0] = *(const s16x8*)(ptr + ((16 * g) ^ sw)); \
    af[rt][1] = *(const s16x8*)(ptr + ((64 + 16 * g) ^ sw)); } }
#define RD_B8(buf) { \
  _Pragma("unroll") for (int ni = 0; ni < 4; ni++) { \
    int row = wc * 64 + ni * 16 + c; \
    const unsigned char* ptr = BS_(buf) + row * 128; \
    int sw = (row & 7) << 4; \
    bfr[ni][0] = *(const s16x8*)(ptr + ((16 * g) ^ sw)); \
    bfr[ni][1] = *(const s16x8*)(ptr + ((64 + 16 * g) ^ sw)); } }
#define MFP(p) { \
  _Pragma("unroll") for (int rt = 0; rt < 2; rt++) \
  _Pragma("unroll") for (int ni = 0; ni < 4; ni++) \
  _Pragma("unroll") for (int kk = 0; kk < 2; kk++) \
    acc[(p) * 2 + rt][ni] = __builtin_amdgcn_mfma_f32_16x16x32_bf16( \
        af[rt][kk], bfr[ni][kk], acc[(p) * 2 + rt][ni], 0, 0, 0); }

__global__ __launch_bounds__(512, 1) void k_gemm8(
    const u16* __restrict__ A, const u16* __restrict__ Bt,
    float* __restrict__ Cv, int M, int N, int K)
{
  __shared__ __attribute__((aligned(16))) unsigned char smem[131072];
  const int tid = threadIdx.x;
  const int w = tid >> 6, l = tid & 63;
  const int c = l & 15, g = l >> 4;
  const int wr = w >> 2, wc = w & 3;

  const int nbx = N >> 8;
  const int nwg = nbx * (M >> 8);
  const int orig = blockIdx.x;
  const int id = (orig & 7) * (nwg >> 3) + (orig >> 3);
  const int m0 = (id / nbx) << 8;
  const int n0 = (id % nbx) << 8;

  const int srcoff = 8 * ((l & 7) ^ ((l >> 3) & 7));
  const int subrow = l >> 3;

  f32x4 acc[8][4];
  #pragma unroll
  for (int i = 0; i < 8; i++)
    #pragma unroll
    for (int j = 0; j < 4; j++)
      acc[i][j] = f32x4{0.f, 0.f, 0.f, 0.f};
  s16x8 af[2][2], bfr[4][2];

  STAGE_HB(0, 0, 0); STAGE_HB(0, 1, 0);
  STAGE_HA(0, 0, 0); STAGE_HA(0, 1, 0);
  STAGE_HB(1, 0, 1); STAGE_HB(1, 1, 1);
  VM4; BARX;

  const int NT2 = K >> 7;
  for (int it = 0; it < NT2; ++it) {
    const int tA = 2 * it, tB = 2 * it + 1;
    const bool st = (it < NT2 - 1);
    RD_A2(0, 0); RD_B8(0); STAGE_HA(1, 0, tB);
    BARX; LGKM0; PRIO1; MFP(0); PRIO0; BARX;
    RD_A2(0, 1); STAGE_HA(1, 1, tB);
    BARX; LGKM0; PRIO1; MFP(1); PRIO0; BARX;
    RD_A2(0, 2); if (st) STAGE_HB(0, 0, tA + 2);
    BARX; LGKM0; PRIO1; MFP(2); PRIO0; BARX;
    RD_A2(0, 3); if (st) STAGE_HB(0, 1, tA + 2);
    BARX; LGKM0; PRIO1; MFP(3); PRIO0;
    if (st) { VM4; } else { VM0; }
    BARX;
    RD_A2(1, 0); RD_B8(1); if (st) STAGE_HA(0, 0, tA + 2);
    BARX; LGKM0; PRIO1; MFP(0); PRIO0; BARX;
    RD_A2(1, 1); if (st) STAGE_HA(0, 1, tA + 2);
    BARX; LGKM0; PRIO1; MFP(1); PRIO0; BARX;
    RD_A2(1, 2); if (st) STAGE_HB(1, 0, tB + 2);
    BARX; LGKM0; PRIO1; MFP(2); PRIO0; BARX;
    RD_A2(1, 3); if (st) STAGE_HB(1, 1, tB + 2);
    BARX; LGKM0; PRIO1; MFP(3); PRIO0;
    if (st) { VM4; }
    BARX;
  }

  #pragma unroll
  for (int mi = 0; mi < 8; mi++)
    #pragma unroll
    for (int ni = 0; ni < 4; ni++)
      #pragma unroll
      for (int r = 0; r < 4; r++) {
        int m = m0 + wr * 128 + 16 * mi + 4 * g + r;
        int n = n0 + wc * 64 + 16 * ni + c;
        Cv[(size_t)m * N + n] = acc[mi][ni][r];
      }
}

// ======== k_rope: RoPE-Q (in place) + RoPE-K (-> swizzled Kg) in ONE launch ========
__global__ void k_rope(u16* __restrict__ C1, const float* __restrict__ fc,
                       const float* __restrict__ fs, unsigned char* __restrict__ Kg){
  const int bid = blockIdx.x;
  if (bid < 32768) {
    int idx = bid * 256 + threadIdx.x;        // M_ * 2048 pairs
    int m = idx >> 11, p = idx & 2047;
    int h = p >> 6, i = p & 63;
    int t = m & (T_ - 1);
    u32* ptr = reinterpret_cast<u32*>(C1 + (size_t)m * NQKV + h * HD_ + 2 * i);
    u32 u = *ptr;
    float x0 = __uint_as_float(u << 16);
    float x1 = __uint_as_float(u & 0xffff0000u);
    float cc = fc[t * 64 + i], ss = fs[t * 64 + i];
    float o0 = x0 * cc - x1 * ss;
    float o1 = x0 * ss + x1 * cc;
    *ptr = (u32)f2bf(o0) | ((u32)f2bf(o1) << 16);
  } else {
    int idx = (bid - 32768) * 256 + threadIdx.x;  // M_ * 512 pairs
    int m = idx >> 9, p = idx & 511;
    int kh = p >> 6, i = p & 63;
    int b = m >> 11, t = m & (T_ - 1);
    u32 u = *reinterpret_cast<const u32*>(C1 + (size_t)m * NQKV + D_ + kh * HD_ + 2 * i);
    float x0 = __uint_as_float(u << 16);
    float x1 = __uint_as_float(u & 0xffff0000u);
    float cc = fc[t * 64 + i], ss = fs[t * 64 + i];
    float o0 = x0 * cc - x1 * ss;
    float o1 = x0 * ss + x1 * cc;
    u32 packed = (u32)f2bf(o0) | ((u32)f2bf(o1) << 16);
    unsigned char* Kbb = Kg + (size_t)(b * HKV_ + kh) * 524288;
    int swb = (((i >> 2) ^ (t & 7)) << 4) | (4 * (i & 3));
    *reinterpret_cast<u32*>(Kbb + (size_t)t * 256 + swb) = packed;
  }
}

// ---- V -> fp16 V^T, tile-major [b][kh][T/64][128][64], kv-bit-permuted + swizzled ----
__global__ void k_v_trans(const u16* __restrict__ C1, unsigned char* __restrict__ Vg){
  __shared__ float tile[32][33];
  int bz = blockIdx.z;                        // b*8+kh
  int t0 = blockIdx.x * 32, d0 = blockIdx.y * 32;
  int tx = threadIdx.x, ty = threadIdx.y;
  int b = bz >> 3, kh = bz & 7;
  const u16* src = C1 + (size_t)(b * T_) * NQKV + D_ + HKV_ * HD_ + kh * HD_;
  #pragma unroll
  for (int i = ty; i < 32; i += 8)
    tile[i][tx] = bf2f(src[(size_t)(t0 + i) * NQKV + d0 + tx]);
  __syncthreads();
  unsigned char* Vbb = Vg + (size_t)bz * 524288;
  #pragma unroll
  for (int i = ty; i < 32; i += 8) {
    int d = d0 + i;
    int k = t0 + tx;
    int tt = k >> 6, kv = k & 63;
    int pp = (kv & 0x23) | ((kv & 0x10) >> 2) | ((kv & 0x0C) << 1);
    int swb = (((pp >> 3) ^ (d & 7)) << 4) | (2 * (pp & 7));
    *reinterpret_cast<_Float16*>(Vbb + (size_t)tt * 16384 + d * 128 + swb) =
        (_Float16)tile[tx][i];
  }
}

// ------- attention: r15 (best): K dbuf LDS (32KB) + V single-buf LDS (16KB) -------
__global__ __launch_bounds__(256, 2) void k_attn(
    const u16* __restrict__ Q,              // C1 roped, (B*T) x NQKV
    const unsigned char* __restrict__ Kg,   // pre-swizzled tiles
    const unsigned char* __restrict__ Vg,   // pre-swizzled permuted tiles
    u16* __restrict__ Ob)                   // (B*T) x 4096
{
  __shared__ __attribute__((aligned(16))) unsigned char smem[49152];
  const int tid = threadIdx.x;
  const int w = tid >> 6, l = tid & 63;
  const int c = l & 15, g = l >> 4;
  const int q0 = blockIdx.x * 128 + w * 32;
  const int h = blockIdx.y, b = blockIdx.z;
  const int kh = h >> 2;
  const unsigned char* Kb_ = Kg + (size_t)(b * HKV_ + kh) * 524288;
  const unsigned char* Vb_ = Vg + (size_t)(b * HKV_ + kh) * 524288;

  const float SCL2 = 0.08838834764831845f * 1.4426950408889634f; // 1/sqrt(128)*log2e
  const float OFF2 = 14.4269504f;                                // 10*log2e

  s16x8 qf[2][4];
  #pragma unroll
  for (int qt = 0; qt < 2; qt++)
    #pragma unroll
    for (int ci = 0; ci < 4; ci++)
      qf[qt][ci] = *reinterpret_cast<const s16x8*>(
          Q + (size_t)(b * T_ + q0 + 16 * qt + c) * NQKV + h * HD_ + 32 * ci + 8 * g);

  f32x4 o[2][8];
  #pragma unroll
  for (int qt = 0; qt < 2; qt++)
    #pragma unroll
    for (int i = 0; i < 8; i++) o[qt][i] = f32x4{0.f, 0.f, 0.f, 0.f};
  float lsum[2] = {0.f, 0.f};

  auto stageK = [&](int bi, int tt) {
    const unsigned char* Ks = Kb_ + (size_t)tt * 16384;
    unsigned char* Kl = smem + bi * 16384;
    #pragma unroll
    for (int i = 0; i < 4; i++) {
      int ch = i * 4 + w;
      gload16(Ks + ch * 1024 + l * 16, Kl + ch * 1024);
    }
  };
  auto stageV = [&](int tt) {
    const unsigned char* Vs = Vb_ + (size_t)tt * 16384;
    unsigned char* Vl = smem + 32768;
    #pragma unroll
    for (int i = 0; i < 4; i++) {
      int ch = i * 4 + w;
      gload16(Vs + ch * 1024 + l * 16, Vl + ch * 1024);
    }
  };

  stageK(0, 0);
  asm volatile("s_waitcnt vmcnt(0)" ::: "memory");
  __syncthreads();

  for (int tt = 0; tt < T_ / 64; ++tt) {
    int cur = tt & 1;
    stageV(tt);                                // V(t): 4 gloads (oldest)
    if (tt < T_ / 64 - 1) stageK(cur ^ 1, tt + 1);  // K(t+1): 4 gloads (newest)
    const unsigned char* Kl = smem + cur * 16384;
    const unsigned char* Vl = smem + 32768;

    f32x4 s[4][2];
    #pragma unroll
    for (int mi = 0; mi < 4; mi++)
      #pragma unroll
      for (int qt = 0; qt < 2; qt++) s[mi][qt] = f32x4{0.f, 0.f, 0.f, 0.f};

    #pragma unroll
    for (int mi = 0; mi < 4; mi++) {
      const int row = 16 * mi + c;
      const int sw = (row & 7) << 4;
      s16x8 kf[4];
      #pragma unroll
      for (int ci = 0; ci < 4; ci++)
        kf[ci] = *reinterpret_cast<const s16x8*>(Kl + row * 256 + ((64 * ci + 16 * g) ^ sw));
      #pragma unroll
      for (int qt = 0; qt < 2; qt++)
        #pragma unroll
        for (int ci = 0; ci < 4; ci++)
          s[mi][qt] = __builtin_amdgcn_mfma_f32_16x16x32_bf16(kf[ci], qf[qt][ci], s[mi][qt], 0, 0, 0);
    }

    // softmax -> packed A-frags for K=32 PV
    f16x8 pa8[2][2];
    #pragma unroll
    for (int qt = 0; qt < 2; qt++)
      #pragma unroll
      for (int mi = 0; mi < 4; mi++)
        #pragma unroll
        for (int r = 0; r < 4; r++) {
          float p = exp2f(s[mi][qt][r] * SCL2 - OFF2);
          lsum[qt] += p;
          pa8[qt][mi >> 1][(mi & 1) * 4 + r] = (_Float16)p;
        }

    // V(t) landed (counted drain: keep K(t+1) in flight)
    if (tt < T_ / 64 - 1) asm volatile("s_waitcnt vmcnt(4)" ::: "memory");
    else                  asm volatile("s_waitcnt vmcnt(0)" ::: "memory");
    __syncthreads();

    #pragma unroll
    for (int cp = 0; cp < 2; cp++)
      #pragma unroll
      for (int dc = 0; dc < 8; dc++) {
        const int d = 16 * dc + c;
        f16x8 v8 = *reinterpret_cast<const f16x8*>(
            Vl + d * 128 + ((64 * cp + 16 * g) ^ ((d & 7) << 4)));
        #pragma unroll
        for (int qt = 0; qt < 2; qt++)
          o[qt][dc] = __builtin_amdgcn_mfma_f32_16x16x32_f16(pa8[qt][cp], v8, o[qt][dc], 0, 0, 0);
      }

    // K(t+1) landed; all waves done with Vbuf -> safe to overwrite next iter
    asm volatile("s_waitcnt vmcnt(0)" ::: "memory");
    __syncthreads();
  }

  #pragma unroll
  for (int qt = 0; qt < 2; qt++) {
    lsum[qt] += __shfl_xor(lsum[qt], 16);
    lsum[qt] += __shfl_xor(lsum[qt], 32);
  }
  float inv[2][4];
  #pragma unroll
  for (int qt = 0; qt < 2; qt++)
    #pragma unroll
    for (int r = 0; r < 4; r++)
      inv[qt][r] = 1.0f / __shfl(lsum[qt], 4 * g + r, 64);

  #pragma unroll
  for (int qt = 0; qt < 2; qt++) {
    u16* Orow = Ob + (size_t)(b * T_ + q0 + 16 * qt) * D_ + h * HD_;
    #pragma unroll
    for (int dc = 0; dc < 8; dc++)
      #pragma unroll
      for (int r = 0; r < 4; r++)
        Orow[(size_t)(4 * g + r) * D_ + 16 * dc + c] = f2bf(o[qt][dc][r] * inv[qt][r]);
  }
}

// ---------------- launch ----------------
extern "C" void kernel_launch(void* const* d_in, const int* in_sizes, int n_in,
                              void* d_out, int out_size, void* d_ws, size_t ws_size,
                              hipStream_t stream)
{
  const float* x  = (const float*)d_in[0];
  const float* fc = (const float*)d_in[1];
  const float* fs = (const float*)d_in[2];
  const float* wq = (const float*)d_in[6];
  const float* wk = (const float*)d_in[7];
  const float* wv = (const float*)d_in[8];
  const float* wo = (const float*)d_in[9];

  unsigned char* w = (unsigned char*)d_ws;
  u16* Xb   = (u16*)(w);                       // 4096x4096 bf16      33,554,432 B
  u16* Wt   = (u16*)(w + 33554432ull);         // 6144x4096 bf16      50,331,648 B
  u16* Wot  = (u16*)(w + 83886080ull);         // 4096x4096 bf16      33,554,432 B
  u16* C1   = (u16*)(w + 117440512ull);        // 4096x6144 bf16      50,331,648 B
  unsigned char* Kg = w + 167772160ull;        // 16 x 512KB swizzled  8,388,608 B
  unsigned char* Vg = w + 176160768ull;        // 16 x 512KB swizzled  8,388,608 B
  u16* Ob   = (u16*)(w + 184549376ull);        // 4096x4096 bf16      33,554,432 B

  // prep: convert x + all 4 weight transposes (one launch)
  k_prep<<<dim3(64, 64, 5), 256, 0, stream>>>(x, wq, wk, wv, wo, Xb, Wt, Wot);

  // QKV: 256x192 8-phase, n-major-within-XCD raster (512 blocks = 2 rounds)
  k_gemm8q<<<512, 512, 0, stream>>>(Xb, Wt, C1, M_, NQKV, D_);

  // rope Q (in place) + rope K (-> Kg), one launch
  k_rope<<<40960, 256, 0, stream>>>(C1, fc, fs, Kg);
  k_v_trans<<<dim3(64, 4, 16), dim3(32, 8), 0, stream>>>(C1, Vg);

  // attn: K dbuf + V single-buf (48KB LDS), proven r15
  k_attn<<<dim3(T_ / 128, H_, B_), 256, 0, stream>>>(C1, Kg, Vg, Ob);

  // out-proj: 256^2 8-phase (256 blocks = exactly 1/CU, tail-free)
  k_gemm8<<<(D_ / 256) * (M_ / 256), 512, 0, stream>>>(Ob, Wot, (float*)d_out, M_, D_, D_);
}